// Round 5
// baseline (516.898 us; speedup 1.0000x reference)
//
#include <hip/hip_runtime.h>
#include <math.h>

#define N_NODES 100000
#define N_EDGES 1600000
#define G_GRAPHS 256
#define IN_F 128
#define H_F 64

#define SCAN_CH 1024
#define PWAVES 1024
#define PCHUNK ((N_NODES + PWAVES - 1) / PWAVES)

// histogram / placement partitioning
#define HRANGE 16384           // nodes per LDS sub-histogram (64 KB)
#define HR 7                   // ranges: 7*16384 >= 100000
#define HB 20                  // edge-chunk blocks per (array,range)
#define HCHUNK (N_EDGES / HB)  // 80000, divisible by 4

typedef unsigned int uint_t;
typedef unsigned short ushort_t;
typedef __attribute__((ext_vector_type(8))) short short8;
typedef __attribute__((ext_vector_type(4))) float floatx4;

__device__ __forceinline__ ushort_t f2bf(float f) {  // round-to-nearest-even
  uint_t u = __float_as_uint(f);
  uint_t r = (u + 0x7fffu + ((u >> 16) & 1u)) >> 16;
  return (ushort_t)r;
}
__device__ __forceinline__ float bflo(uint_t u) { return __uint_as_float(u << 16); }
__device__ __forceinline__ float bfhi(uint_t u) { return __uint_as_float(u & 0xffff0000u); }

// ---------------------------------------------------------------------------
// 1. LDS-privatized degree histograms -> per-block partials (no global atomics)
// ---------------------------------------------------------------------------
__global__ __launch_bounds__(256) void hist_kernel(
    const int* __restrict__ src, const int* __restrict__ dst,
    int* __restrict__ partials /* [2][HB][N_NODES] */) {
  __shared__ int hist[HRANGE];
  const int a = blockIdx.x / (HR * HB);
  const int rem = blockIdx.x % (HR * HB);
  const int r = rem / HB;
  const int b = rem % HB;
  const int base = r * HRANGE;
  const int width = min(base + HRANGE, N_NODES) - base;

  for (int i = threadIdx.x; i < HRANGE; i += 256) hist[i] = 0;
  __syncthreads();

  const int* keys = a ? dst : src;
  const uint4* k4 = (const uint4*)(keys + b * HCHUNK);
  for (int i = threadIdx.x; i < HCHUNK / 4; i += 256) {
    uint4 v = k4[i];
    int t;
    t = (int)v.x - base; if ((unsigned)t < (unsigned)width) atomicAdd(&hist[t], 1);
    t = (int)v.y - base; if ((unsigned)t < (unsigned)width) atomicAdd(&hist[t], 1);
    t = (int)v.z - base; if ((unsigned)t < (unsigned)width) atomicAdd(&hist[t], 1);
    t = (int)v.w - base; if ((unsigned)t < (unsigned)width) atomicAdd(&hist[t], 1);
  }
  __syncthreads();

  int* outp = partials + ((size_t)a * HB + b) * N_NODES + base;
  for (int i = threadIdx.x; i < width; i += 256) outp[i] = hist[i];
}

// reduce partials -> cnt_in + fused ns/nd
__global__ __launch_bounds__(256) void hist_reduce_kernel(
    const int* __restrict__ partials, int* __restrict__ cnt_in,
    float* __restrict__ ns, float* __restrict__ nd) {
  int i = blockIdx.x * blockDim.x + threadIdx.x;
  if (i >= 2 * N_NODES) return;
  int a = i / N_NODES, node = i % N_NODES;
  const int* p = partials + (size_t)a * HB * N_NODES + node;
  int s = 0;
#pragma unroll
  for (int b = 0; b < HB; ++b) s += p[(size_t)b * N_NODES];
  float nrm = rsqrtf(fmaxf((float)s, 1.0f));
  if (a == 0) { ns[node] = nrm; }
  else        { cnt_in[node] = s; nd[node] = nrm; }
}

// ---------------------------------------------------------------------------
// 2. Exclusive scan of cnt_in -> row_ptr
// ---------------------------------------------------------------------------
__global__ __launch_bounds__(256) void scanA_kernel(
    const int* __restrict__ in, int* __restrict__ out, int* __restrict__ bsums, int n) {
  __shared__ int ts[256];
  const int tid = threadIdx.x;
  const int base = blockIdx.x * SCAN_CH + tid * 4;
  int v[4], pre[4], s = 0;
#pragma unroll
  for (int k = 0; k < 4; ++k) {
    v[k] = (base + k < n) ? in[base + k] : 0;
    pre[k] = s;
    s += v[k];
  }
  ts[tid] = s;
  __syncthreads();
  for (int off = 1; off < 256; off <<= 1) {
    int t = (tid >= off) ? ts[tid - off] : 0;
    __syncthreads();
    ts[tid] += t;
    __syncthreads();
  }
  int excl = (tid == 0) ? 0 : ts[tid - 1];
#pragma unroll
  for (int k = 0; k < 4; ++k)
    if (base + k < n) out[base + k] = excl + pre[k];
  if (tid == 255) bsums[blockIdx.x] = ts[255];
}

__global__ __launch_bounds__(256) void scanB_kernel(int* __restrict__ bsums, int nb) {
  __shared__ int ts[256];
  const int tid = threadIdx.x;
  ts[tid] = (tid < nb) ? bsums[tid] : 0;
  __syncthreads();
  for (int off = 1; off < 256; off <<= 1) {
    int t = (tid >= off) ? ts[tid - off] : 0;
    __syncthreads();
    ts[tid] += t;
    __syncthreads();
  }
  if (tid < nb) bsums[tid] = (tid == 0) ? 0 : ts[tid - 1];
}

__global__ __launch_bounds__(256) void scanC_kernel(
    int* __restrict__ out, const int* __restrict__ bsums, int n) {
  int i = blockIdx.x * blockDim.x + threadIdx.x;
  if (i < n) out[i] += bsums[i / SCAN_CH];
}

// ---------------------------------------------------------------------------
// 3a. Chunk offsets: coff[b][v] = row_ptr[v] + sum_{b'<b} dst_partials[b'][v]
//     (written into the dead a=0 partials region)
// ---------------------------------------------------------------------------
__global__ __launch_bounds__(256) void coff_kernel(
    const int* __restrict__ row_ptr, int* __restrict__ partials) {
  int v = blockIdx.x * blockDim.x + threadIdx.x;
  if (v >= N_NODES) return;
  const int* pin = partials + (size_t)HB * N_NODES;  // a=1 (dst) partials
  int* pout = partials;                              // a=0 region reused
  int run = row_ptr[v];
#pragma unroll
  for (int b = 0; b < HB; ++b) {
    int c = pin[(size_t)b * N_NODES + v];
    pout[(size_t)b * N_NODES + v] = run;
    run += c;
  }
}

// ---------------------------------------------------------------------------
// 3b. Edge placement into CSR via LDS cursors (no global atomics)
//     grid = HR * HB = 140 blocks
// ---------------------------------------------------------------------------
__global__ __launch_bounds__(256) void place_kernel(
    const int* __restrict__ src, const int* __restrict__ dst,
    const float* __restrict__ ew, const int* __restrict__ coff,
    uint2* __restrict__ csr) {
  __shared__ int cur[HRANGE];
  const int r = blockIdx.x / HB;
  const int b = blockIdx.x % HB;
  const int base = r * HRANGE;
  const int width = min(base + HRANGE, N_NODES) - base;

  for (int i = threadIdx.x; i < width; i += 256)
    cur[i] = coff[(size_t)b * N_NODES + base + i];
  __syncthreads();

  const int e0 = b * HCHUNK;
  const uint4* d4 = (const uint4*)(dst + e0);
  for (int i = threadIdx.x; i < HCHUNK / 4; i += 256) {
    uint4 v = d4[i];
    int e = e0 + i * 4;
#pragma unroll
    for (int k = 0; k < 4; ++k) {
      int dv = (int)(k == 0 ? v.x : k == 1 ? v.y : k == 2 ? v.z : v.w);
      int t = dv - base;
      if ((unsigned)t < (unsigned)width) {
        int slot = atomicAdd(&cur[t], 1);
        csr[slot] = make_uint2((uint_t)src[e + k], __float_as_uint(ew[e + k]));
      }
    }
  }
}

// ---------------------------------------------------------------------------
// 4. MFMA GEMM: T[i,:] = bf16(ns[i] * (X[i,:] @ W))
// ---------------------------------------------------------------------------
template <int K, bool AFP32>
__global__ __launch_bounds__(256) void gemm_mfma_kernel(
    const void* __restrict__ Xin, const float* __restrict__ W,
    const float* __restrict__ ns, ushort_t* __restrict__ T, int ntiles) {
  constexpr int CH = K / 32;
  constexpr int WROW = K + 8;
  __shared__ __align__(16) ushort_t Wt[64 * WROW];
  const int tid = threadIdx.x;

  for (int i = tid; i < K * 64; i += 256) {
    int k = i >> 6, nn = i & 63;
    Wt[nn * WROW + k] = f2bf(W[i]);
  }
  __syncthreads();

  const int wave = tid >> 6;
  const int lane = tid & 63;
  const int tile = blockIdx.x * 4 + wave;
  if (tile >= ntiles) return;
  const int m = lane & 15;
  const int q = lane >> 4;
  const int node0 = tile * 16;

  short8 afrag[CH];
  if (AFP32) {
    const float* xr = (const float*)Xin + (size_t)(node0 + m) * K + q * 8;
#pragma unroll
    for (int c = 0; c < CH; ++c) {
      float4 xa = *(const float4*)(xr + c * 32);
      float4 xb = *(const float4*)(xr + c * 32 + 4);
      short8 a;
      a[0] = (short)f2bf(xa.x); a[1] = (short)f2bf(xa.y);
      a[2] = (short)f2bf(xa.z); a[3] = (short)f2bf(xa.w);
      a[4] = (short)f2bf(xb.x); a[5] = (short)f2bf(xb.y);
      a[6] = (short)f2bf(xb.z); a[7] = (short)f2bf(xb.w);
      afrag[c] = a;
    }
  } else {
    const ushort_t* xr = (const ushort_t*)Xin + (size_t)(node0 + m) * K + q * 8;
#pragma unroll
    for (int c = 0; c < CH; ++c)
      afrag[c] = *(const short8*)(xr + c * 32);
  }

  floatx4 acc[4];
#pragma unroll
  for (int t = 0; t < 4; ++t) acc[t] = (floatx4){0.f, 0.f, 0.f, 0.f};

#pragma unroll
  for (int t = 0; t < 4; ++t) {
    const ushort_t* wr = &Wt[(t * 16 + m) * WROW + q * 8];
#pragma unroll
    for (int c = 0; c < CH; ++c) {
      short8 bfrag = *(const short8*)(wr + c * 32);
      acc[t] = __builtin_amdgcn_mfma_f32_16x16x32_bf16(afrag[c], bfrag, acc[t], 0, 0, 0);
    }
  }

  float4 nsv = *(const float4*)(ns + node0 + q * 4);
  const float nsa[4] = {nsv.x, nsv.y, nsv.z, nsv.w};
#pragma unroll
  for (int t = 0; t < 4; ++t) {
#pragma unroll
    for (int r = 0; r < 4; ++r) {
      int node = node0 + q * 4 + r;
      T[(size_t)node * 64 + t * 16 + m] = f2bf(acc[t][r] * nsa[r]);
    }
  }
}

// ---------------------------------------------------------------------------
// 5. CSR gather (bf16 T), 16 edges in flight per wave-iteration.
// ---------------------------------------------------------------------------
__global__ __launch_bounds__(256) void gather_kernel(
    const uint2* __restrict__ csr, const int* __restrict__ row_ptr,
    const int* __restrict__ cnt_in, const ushort_t* __restrict__ T,
    const float* __restrict__ nd, const float* __restrict__ b,
    ushort_t* __restrict__ H, int n) {
  int id = blockIdx.x * blockDim.x + threadIdx.x;
  int v = id >> 6;
  if (v >= n) return;
  const int lane = threadIdx.x & 63;
  const int g = lane >> 3, l = lane & 7;
  const int start = row_ptr[v];
  const int cnt = cnt_in[v];

  float acc[8] = {0, 0, 0, 0, 0, 0, 0, 0};
  for (int k = 0; k < cnt; k += 16) {
    int i1 = k + g, i2 = k + 8 + g;
    uint2 e1 = csr[start + min(i1, cnt - 1)];
    uint2 e2 = csr[start + min(i2, cnt - 1)];
    float w1 = (i1 < cnt) ? __uint_as_float(e1.y) : 0.0f;
    float w2 = (i2 < cnt) ? __uint_as_float(e2.y) : 0.0f;
    uint4 p1 = *((const uint4*)(T + (size_t)e1.x * 64) + l);
    uint4 p2 = *((const uint4*)(T + (size_t)e2.x * 64) + l);
    acc[0] = fmaf(bflo(p1.x), w1, acc[0]);
    acc[1] = fmaf(bfhi(p1.x), w1, acc[1]);
    acc[2] = fmaf(bflo(p1.y), w1, acc[2]);
    acc[3] = fmaf(bfhi(p1.y), w1, acc[3]);
    acc[4] = fmaf(bflo(p1.z), w1, acc[4]);
    acc[5] = fmaf(bfhi(p1.z), w1, acc[5]);
    acc[6] = fmaf(bflo(p1.w), w1, acc[6]);
    acc[7] = fmaf(bfhi(p1.w), w1, acc[7]);
    acc[0] = fmaf(bflo(p2.x), w2, acc[0]);
    acc[1] = fmaf(bfhi(p2.x), w2, acc[1]);
    acc[2] = fmaf(bflo(p2.y), w2, acc[2]);
    acc[3] = fmaf(bfhi(p2.y), w2, acc[3]);
    acc[4] = fmaf(bflo(p2.z), w2, acc[4]);
    acc[5] = fmaf(bfhi(p2.z), w2, acc[5]);
    acc[6] = fmaf(bflo(p2.w), w2, acc[6]);
    acc[7] = fmaf(bfhi(p2.w), w2, acc[7]);
  }
#pragma unroll
  for (int off = 8; off < 64; off <<= 1) {
#pragma unroll
    for (int i = 0; i < 8; ++i) acc[i] += __shfl_xor(acc[i], off, 64);
  }
  if (g == 0) {
    float ndv = nd[v];
    float4 b0 = *(const float4*)&b[l * 8];
    float4 b1 = *(const float4*)&b[l * 8 + 4];
    uint4 o;
    o.x = (uint_t)f2bf(fmaxf(fmaf(acc[0], ndv, b0.x), 0.f)) |
          ((uint_t)f2bf(fmaxf(fmaf(acc[1], ndv, b0.y), 0.f)) << 16);
    o.y = (uint_t)f2bf(fmaxf(fmaf(acc[2], ndv, b0.z), 0.f)) |
          ((uint_t)f2bf(fmaxf(fmaf(acc[3], ndv, b0.w), 0.f)) << 16);
    o.z = (uint_t)f2bf(fmaxf(fmaf(acc[4], ndv, b1.x), 0.f)) |
          ((uint_t)f2bf(fmaxf(fmaf(acc[5], ndv, b1.y), 0.f)) << 16);
    o.w = (uint_t)f2bf(fmaxf(fmaf(acc[6], ndv, b1.z), 0.f)) |
          ((uint_t)f2bf(fmaxf(fmaf(acc[7], ndv, b1.w), 0.f)) << 16);
    *((uint4*)(H + (size_t)v * 64) + l) = o;
  }
}

// ---------------------------------------------------------------------------
// 6. Segmented pool over sorted gid (bf16 H)
// ---------------------------------------------------------------------------
__global__ __launch_bounds__(256) void pool_seg_kernel(
    const ushort_t* __restrict__ H, const int* __restrict__ gid,
    float* __restrict__ pooled, float* __restrict__ counts, int n) {
  int wid = (blockIdx.x * blockDim.x + threadIdx.x) >> 6;
  int j = threadIdx.x & 63;
  int s = wid * PCHUNK;
  if (s >= n) return;
  int e = min(s + PCHUNK, n);
  float acc = 0.0f;
  int cur = gid[s];
  int runlen = 0;
  for (int node = s; node < e; ++node) {
    int g = gid[node];
    if (g != cur) {
      atomicAdd(&pooled[cur * 64 + j], acc);
      if (j == 0) atomicAdd(&counts[cur], (float)runlen);
      acc = 0.0f;
      runlen = 0;
      cur = g;
    }
    acc += bflo((uint_t)H[(size_t)node * 64 + j]);
    ++runlen;
  }
  atomicAdd(&pooled[cur * 64 + j], acc);
  if (j == 0) atomicAdd(&counts[cur], (float)runlen);
}

// ---------------------------------------------------------------------------
// 7. MLP head
// ---------------------------------------------------------------------------
__global__ __launch_bounds__(256) void mlp_kernel(
    const float* __restrict__ pooled, const float* __restrict__ counts,
    const float* __restrict__ Dw1, const float* __restrict__ Db1,
    const float* __restrict__ Dw2, const float* __restrict__ Db2,
    const float* __restrict__ Dw3, const float* __restrict__ Db3,
    float* __restrict__ out) {
  int g = blockIdx.x * blockDim.x + threadIdx.x;
  if (g < G_GRAPHS) {
    float inv = 1.0f / fmaxf(counts[g], 1.0f);
    float p[64];
#pragma unroll
    for (int k = 0; k < 64; ++k) p[k] = pooled[g * 64 + k] * inv;
    float h1[16];
#pragma unroll
    for (int o = 0; o < 16; ++o) {
      float a = Db1[o];
      for (int k = 0; k < 64; ++k) a = fmaf(p[k], Dw1[k * 16 + o], a);
      h1[o] = fmaxf(a, 0.0f);
    }
    float h2[8];
#pragma unroll
    for (int o = 0; o < 8; ++o) {
      float a = Db2[o];
      for (int k = 0; k < 16; ++k) a = fmaf(h1[k], Dw2[k * 8 + o], a);
      h2[o] = fmaxf(a, 0.0f);
    }
    float a = Db3[0];
#pragma unroll
    for (int k = 0; k < 8; ++k) a = fmaf(h2[k], Dw3[k], a);
    out[g] = 1.0f / (1.0f + expf(-a));
  }
}

// ---------------------------------------------------------------------------
extern "C" void kernel_launch(void* const* d_in, const int* in_sizes, int n_in,
                              void* d_out, int out_size, void* d_ws, size_t ws_size,
                              hipStream_t stream) {
  const float* x   = (const float*)d_in[0];
  const int*   src = (const int*)  d_in[1];
  const int*   dst = (const int*)  d_in[2];
  const float* ew  = (const float*)d_in[3];
  const int*   gid = (const int*)  d_in[4];
  const float* W1  = (const float*)d_in[5];
  const float* b1  = (const float*)d_in[6];
  const float* W2  = (const float*)d_in[7];
  const float* b2  = (const float*)d_in[8];
  const float* W3  = (const float*)d_in[9];
  const float* b3  = (const float*)d_in[10];
  const float* Dw1 = (const float*)d_in[11];
  const float* Db1 = (const float*)d_in[12];
  const float* Dw2 = (const float*)d_in[13];
  const float* Db2 = (const float*)d_in[14];
  const float* Dw3 = (const float*)d_in[15];
  const float* Db3 = (const float*)d_in[16];
  float* out = (float*)d_out;

  // workspace layout
  char* ws = (char*)d_ws;
  ushort_t* Tb   = (ushort_t*)ws;                       // N*64 bf16
  ushort_t* Hb   = Tb + (size_t)N_NODES * 64;           // N*64 bf16
  float* ns      = (float*)(Hb + (size_t)N_NODES * 64); // N
  float* nd      = ns + N_NODES;                        // N
  float* pooled  = nd + N_NODES;                        // G*64
  float* counts  = pooled + G_GRAPHS * 64;              // G
  int*   cnt_in  = (int*)(counts + G_GRAPHS);           // N
  int*   row_ptr = cnt_in + N_NODES;                    // N
  int*   bsums   = row_ptr + N_NODES;                   // 128
  uint2* csr     = (uint2*)(bsums + 128);               // E (8B each)
  // partials alias Tb/Hb (dead before gemm1 runs): 2*HB*N ints = 16 MB <= 25.6 MB
  int*   partials = (int*)Tb;

  const int NTILES  = N_NODES / 16;                     // 6250
  const int NB_N    = (N_NODES + 255) / 256;
  const int NB_SCAN = (N_NODES + SCAN_CH - 1) / SCAN_CH;
  const int NB_HIST = 2 * HR * HB;                      // 280
  const int NB_RED  = (2 * N_NODES + 255) / 256;
  const int NB_PLACE= HR * HB;                          // 140
  const int NB_GEMM = (NTILES + 3) / 4;
  const int NB_GATH = (N_NODES * 64 + 255) / 256;
  const int NB_POOL = (PWAVES * 64) / 256;

  // ---- degrees (privatized hist), norms, CSR build (atomic-free)
  hist_kernel<<<NB_HIST, 256, 0, stream>>>(src, dst, partials);
  hist_reduce_kernel<<<NB_RED, 256, 0, stream>>>(partials, cnt_in, ns, nd);
  scanA_kernel<<<NB_SCAN, 256, 0, stream>>>(cnt_in, row_ptr, bsums, N_NODES);
  scanB_kernel<<<1, 256, 0, stream>>>(bsums, NB_SCAN);
  scanC_kernel<<<NB_N, 256, 0, stream>>>(row_ptr, bsums, N_NODES);
  coff_kernel<<<NB_N, 256, 0, stream>>>(row_ptr, partials);
  place_kernel<<<NB_PLACE, 256, 0, stream>>>(src, dst, ew, partials, csr);

  // ---- layer 1: x(fp32,128) -> Tb -> Hb
  gemm_mfma_kernel<IN_F, true><<<NB_GEMM, 256, 0, stream>>>(x, W1, ns, Tb, NTILES);
  gather_kernel<<<NB_GATH, 256, 0, stream>>>(csr, row_ptr, cnt_in, Tb, nd, b1, Hb, N_NODES);
  // ---- layer 2
  gemm_mfma_kernel<H_F, false><<<NB_GEMM, 256, 0, stream>>>(Hb, W2, ns, Tb, NTILES);
  gather_kernel<<<NB_GATH, 256, 0, stream>>>(csr, row_ptr, cnt_in, Tb, nd, b2, Hb, N_NODES);
  // ---- layer 3
  gemm_mfma_kernel<H_F, false><<<NB_GEMM, 256, 0, stream>>>(Hb, W3, ns, Tb, NTILES);
  gather_kernel<<<NB_GATH, 256, 0, stream>>>(csr, row_ptr, cnt_in, Tb, nd, b3, Hb, N_NODES);

  // ---- pool + MLP
  hipMemsetAsync(pooled, 0, (size_t)(G_GRAPHS * 64 + G_GRAPHS) * sizeof(float), stream);
  pool_seg_kernel<<<NB_POOL, 256, 0, stream>>>(Hb, gid, pooled, counts, N_NODES);
  mlp_kernel<<<1, 256, 0, stream>>>(pooled, counts, Dw1, Db1, Dw2, Db2, Dw3, Db3, out);
}

// Round 6
// 432.534 us; speedup vs baseline: 1.1950x; 1.1950x over previous
//
#include <hip/hip_runtime.h>
#include <math.h>

#define N_NODES 100000
#define N_EDGES 1600000
#define G_GRAPHS 256
#define IN_F 128
#define H_F 64

#define SCAN_CH 1024
#define PWAVES 1024
#define PCHUNK ((N_NODES + PWAVES - 1) / PWAVES)

// histogram / placement partitioning
#define HRANGE 8192            // nodes per LDS window (32 KB -> 5 blocks/CU)
#define HR 13                  // ceil(100000/8192)
#define HB 64                  // edge chunks
#define HCHUNK (N_EDGES / HB)  // 25000, divisible by 4

typedef unsigned int uint_t;
typedef unsigned short ushort_t;
typedef __attribute__((ext_vector_type(8))) short short8;
typedef __attribute__((ext_vector_type(4))) float floatx4;

__device__ __forceinline__ ushort_t f2bf(float f) {  // round-to-nearest-even
  uint_t u = __float_as_uint(f);
  uint_t r = (u + 0x7fffu + ((u >> 16) & 1u)) >> 16;
  return (ushort_t)r;
}
__device__ __forceinline__ float bflo(uint_t u) { return __uint_as_float(u << 16); }
__device__ __forceinline__ float bfhi(uint_t u) { return __uint_as_float(u & 0xffff0000u); }

// ---------------------------------------------------------------------------
// 1. LDS-privatized histogram of one key array -> partials [HB][N]
//    grid = HR * HB = 832
// ---------------------------------------------------------------------------
__global__ __launch_bounds__(256) void hist_kernel(
    const int* __restrict__ keys, int* __restrict__ partials) {
  __shared__ int hist[HRANGE];
  const int r = blockIdx.x / HB;
  const int b = blockIdx.x % HB;
  const int base = r * HRANGE;
  const int width = min(base + HRANGE, N_NODES) - base;

  for (int i = threadIdx.x; i < HRANGE; i += 256) hist[i] = 0;
  __syncthreads();

  const uint4* k4 = (const uint4*)(keys + b * HCHUNK);
  for (int i = threadIdx.x; i < HCHUNK / 4; i += 256) {
    uint4 v = k4[i];
    int t;
    t = (int)v.x - base; if ((unsigned)t < (unsigned)width) atomicAdd(&hist[t], 1);
    t = (int)v.y - base; if ((unsigned)t < (unsigned)width) atomicAdd(&hist[t], 1);
    t = (int)v.z - base; if ((unsigned)t < (unsigned)width) atomicAdd(&hist[t], 1);
    t = (int)v.w - base; if ((unsigned)t < (unsigned)width) atomicAdd(&hist[t], 1);
  }
  __syncthreads();

  int* outp = partials + (size_t)b * N_NODES + base;
  for (int i = threadIdx.x; i < width; i += 256) outp[i] = hist[i];
}

// reduce dst partials -> cnt_in + nd
__global__ __launch_bounds__(256) void reduce_dst_kernel(
    const int* __restrict__ partials, int* __restrict__ cnt_in,
    float* __restrict__ nd) {
  int v = blockIdx.x * blockDim.x + threadIdx.x;
  if (v >= N_NODES) return;
  const int* p = partials + v;
  int s = 0;
#pragma unroll
  for (int b = 0; b < HB; ++b) s += p[(size_t)b * N_NODES];
  cnt_in[v] = s;
  nd[v] = rsqrtf(fmaxf((float)s, 1.0f));
}

// reduce src partials -> ns
__global__ __launch_bounds__(256) void reduce_src_kernel(
    const int* __restrict__ partials, float* __restrict__ ns) {
  int v = blockIdx.x * blockDim.x + threadIdx.x;
  if (v >= N_NODES) return;
  const int* p = partials + v;
  int s = 0;
#pragma unroll
  for (int b = 0; b < HB; ++b) s += p[(size_t)b * N_NODES];
  ns[v] = rsqrtf(fmaxf((float)s, 1.0f));
}

// ---------------------------------------------------------------------------
// 2. Exclusive scan of cnt_in -> row_ptr
// ---------------------------------------------------------------------------
__global__ __launch_bounds__(256) void scanA_kernel(
    const int* __restrict__ in, int* __restrict__ out, int* __restrict__ bsums, int n) {
  __shared__ int ts[256];
  const int tid = threadIdx.x;
  const int base = blockIdx.x * SCAN_CH + tid * 4;
  int v[4], pre[4], s = 0;
#pragma unroll
  for (int k = 0; k < 4; ++k) {
    v[k] = (base + k < n) ? in[base + k] : 0;
    pre[k] = s;
    s += v[k];
  }
  ts[tid] = s;
  __syncthreads();
  for (int off = 1; off < 256; off <<= 1) {
    int t = (tid >= off) ? ts[tid - off] : 0;
    __syncthreads();
    ts[tid] += t;
    __syncthreads();
  }
  int excl = (tid == 0) ? 0 : ts[tid - 1];
#pragma unroll
  for (int k = 0; k < 4; ++k)
    if (base + k < n) out[base + k] = excl + pre[k];
  if (tid == 255) bsums[blockIdx.x] = ts[255];
}

__global__ __launch_bounds__(256) void scanB_kernel(int* __restrict__ bsums, int nb) {
  __shared__ int ts[256];
  const int tid = threadIdx.x;
  ts[tid] = (tid < nb) ? bsums[tid] : 0;
  __syncthreads();
  for (int off = 1; off < 256; off <<= 1) {
    int t = (tid >= off) ? ts[tid - off] : 0;
    __syncthreads();
    ts[tid] += t;
    __syncthreads();
  }
  if (tid < nb) bsums[tid] = (tid == 0) ? 0 : ts[tid - 1];
}

__global__ __launch_bounds__(256) void scanC_kernel(
    int* __restrict__ out, const int* __restrict__ bsums, int n) {
  int i = blockIdx.x * blockDim.x + threadIdx.x;
  if (i < n) out[i] += bsums[i / SCAN_CH];
}

// ---------------------------------------------------------------------------
// 3a. In-place chunk offsets: partials[b][v] := row_ptr[v] + sum_{b'<b} partials[b'][v]
// ---------------------------------------------------------------------------
__global__ __launch_bounds__(256) void coff_kernel(
    const int* __restrict__ row_ptr, int* __restrict__ partials) {
  int v = blockIdx.x * blockDim.x + threadIdx.x;
  if (v >= N_NODES) return;
  int run = row_ptr[v];
#pragma unroll
  for (int b = 0; b < HB; ++b) {
    int* p = partials + (size_t)b * N_NODES + v;
    int c = *p;
    *p = run;
    run += c;
  }
}

// ---------------------------------------------------------------------------
// 3b. Edge placement into CSR via LDS cursors (no global atomics)
//     grid = HR * HB = 832, 32 KB LDS
// ---------------------------------------------------------------------------
__global__ __launch_bounds__(256) void place_kernel(
    const int* __restrict__ src, const int* __restrict__ dst,
    const float* __restrict__ ew, const int* __restrict__ coff,
    uint2* __restrict__ csr) {
  __shared__ int cur[HRANGE];
  const int r = blockIdx.x / HB;
  const int b = blockIdx.x % HB;
  const int base = r * HRANGE;
  const int width = min(base + HRANGE, N_NODES) - base;

  for (int i = threadIdx.x; i < width; i += 256)
    cur[i] = coff[(size_t)b * N_NODES + base + i];
  __syncthreads();

  const int e0 = b * HCHUNK;
  const uint4* d4 = (const uint4*)(dst + e0);
  for (int i = threadIdx.x; i < HCHUNK / 4; i += 256) {
    uint4 v = d4[i];
    int e = e0 + i * 4;
#pragma unroll
    for (int k = 0; k < 4; ++k) {
      int dv = (int)(k == 0 ? v.x : k == 1 ? v.y : k == 2 ? v.z : v.w);
      int t = dv - base;
      if ((unsigned)t < (unsigned)width) {
        int slot = atomicAdd(&cur[t], 1);
        csr[slot] = make_uint2((uint_t)src[e + k], __float_as_uint(ew[e + k]));
      }
    }
  }
}

// ---------------------------------------------------------------------------
// 4. MFMA GEMM: T[i,:] = bf16(ns[i] * (X[i,:] @ W))
// ---------------------------------------------------------------------------
template <int K, bool AFP32>
__global__ __launch_bounds__(256) void gemm_mfma_kernel(
    const void* __restrict__ Xin, const float* __restrict__ W,
    const float* __restrict__ ns, ushort_t* __restrict__ T, int ntiles) {
  constexpr int CH = K / 32;
  constexpr int WROW = K + 8;
  __shared__ __align__(16) ushort_t Wt[64 * WROW];
  const int tid = threadIdx.x;

  for (int i = tid; i < K * 64; i += 256) {
    int k = i >> 6, nn = i & 63;
    Wt[nn * WROW + k] = f2bf(W[i]);
  }
  __syncthreads();

  const int wave = tid >> 6;
  const int lane = tid & 63;
  const int tile = blockIdx.x * 4 + wave;
  if (tile >= ntiles) return;
  const int m = lane & 15;
  const int q = lane >> 4;
  const int node0 = tile * 16;

  short8 afrag[CH];
  if (AFP32) {
    const float* xr = (const float*)Xin + (size_t)(node0 + m) * K + q * 8;
#pragma unroll
    for (int c = 0; c < CH; ++c) {
      float4 xa = *(const float4*)(xr + c * 32);
      float4 xb = *(const float4*)(xr + c * 32 + 4);
      short8 a;
      a[0] = (short)f2bf(xa.x); a[1] = (short)f2bf(xa.y);
      a[2] = (short)f2bf(xa.z); a[3] = (short)f2bf(xa.w);
      a[4] = (short)f2bf(xb.x); a[5] = (short)f2bf(xb.y);
      a[6] = (short)f2bf(xb.z); a[7] = (short)f2bf(xb.w);
      afrag[c] = a;
    }
  } else {
    const ushort_t* xr = (const ushort_t*)Xin + (size_t)(node0 + m) * K + q * 8;
#pragma unroll
    for (int c = 0; c < CH; ++c)
      afrag[c] = *(const short8*)(xr + c * 32);
  }

  floatx4 acc[4];
#pragma unroll
  for (int t = 0; t < 4; ++t) acc[t] = (floatx4){0.f, 0.f, 0.f, 0.f};

#pragma unroll
  for (int t = 0; t < 4; ++t) {
    const ushort_t* wr = &Wt[(t * 16 + m) * WROW + q * 8];
#pragma unroll
    for (int c = 0; c < CH; ++c) {
      short8 bfrag = *(const short8*)(wr + c * 32);
      acc[t] = __builtin_amdgcn_mfma_f32_16x16x32_bf16(afrag[c], bfrag, acc[t], 0, 0, 0);
    }
  }

  float4 nsv = *(const float4*)(ns + node0 + q * 4);
  const float nsa[4] = {nsv.x, nsv.y, nsv.z, nsv.w};
#pragma unroll
  for (int t = 0; t < 4; ++t) {
#pragma unroll
    for (int r = 0; r < 4; ++r) {
      int node = node0 + q * 4 + r;
      T[(size_t)node * 64 + t * 16 + m] = f2bf(acc[t][r] * nsa[r]);
    }
  }
}

// ---------------------------------------------------------------------------
// 5. CSR gather (bf16 T), 16 edges in flight per wave-iteration.
// ---------------------------------------------------------------------------
__global__ __launch_bounds__(256) void gather_kernel(
    const uint2* __restrict__ csr, const int* __restrict__ row_ptr,
    const int* __restrict__ cnt_in, const ushort_t* __restrict__ T,
    const float* __restrict__ nd, const float* __restrict__ b,
    ushort_t* __restrict__ H, int n) {
  int id = blockIdx.x * blockDim.x + threadIdx.x;
  int v = id >> 6;
  if (v >= n) return;
  const int lane = threadIdx.x & 63;
  const int g = lane >> 3, l = lane & 7;
  const int start = row_ptr[v];
  const int cnt = cnt_in[v];

  float acc[8] = {0, 0, 0, 0, 0, 0, 0, 0};
  for (int k = 0; k < cnt; k += 16) {
    int i1 = k + g, i2 = k + 8 + g;
    uint2 e1 = csr[start + min(i1, cnt - 1)];
    uint2 e2 = csr[start + min(i2, cnt - 1)];
    float w1 = (i1 < cnt) ? __uint_as_float(e1.y) : 0.0f;
    float w2 = (i2 < cnt) ? __uint_as_float(e2.y) : 0.0f;
    uint4 p1 = *((const uint4*)(T + (size_t)e1.x * 64) + l);
    uint4 p2 = *((const uint4*)(T + (size_t)e2.x * 64) + l);
    acc[0] = fmaf(bflo(p1.x), w1, acc[0]);
    acc[1] = fmaf(bfhi(p1.x), w1, acc[1]);
    acc[2] = fmaf(bflo(p1.y), w1, acc[2]);
    acc[3] = fmaf(bfhi(p1.y), w1, acc[3]);
    acc[4] = fmaf(bflo(p1.z), w1, acc[4]);
    acc[5] = fmaf(bfhi(p1.z), w1, acc[5]);
    acc[6] = fmaf(bflo(p1.w), w1, acc[6]);
    acc[7] = fmaf(bfhi(p1.w), w1, acc[7]);
    acc[0] = fmaf(bflo(p2.x), w2, acc[0]);
    acc[1] = fmaf(bfhi(p2.x), w2, acc[1]);
    acc[2] = fmaf(bflo(p2.y), w2, acc[2]);
    acc[3] = fmaf(bfhi(p2.y), w2, acc[3]);
    acc[4] = fmaf(bflo(p2.z), w2, acc[4]);
    acc[5] = fmaf(bfhi(p2.z), w2, acc[5]);
    acc[6] = fmaf(bflo(p2.w), w2, acc[6]);
    acc[7] = fmaf(bfhi(p2.w), w2, acc[7]);
  }
#pragma unroll
  for (int off = 8; off < 64; off <<= 1) {
#pragma unroll
    for (int i = 0; i < 8; ++i) acc[i] += __shfl_xor(acc[i], off, 64);
  }
  if (g == 0) {
    float ndv = nd[v];
    float4 b0 = *(const float4*)&b[l * 8];
    float4 b1 = *(const float4*)&b[l * 8 + 4];
    uint4 o;
    o.x = (uint_t)f2bf(fmaxf(fmaf(acc[0], ndv, b0.x), 0.f)) |
          ((uint_t)f2bf(fmaxf(fmaf(acc[1], ndv, b0.y), 0.f)) << 16);
    o.y = (uint_t)f2bf(fmaxf(fmaf(acc[2], ndv, b0.z), 0.f)) |
          ((uint_t)f2bf(fmaxf(fmaf(acc[3], ndv, b0.w), 0.f)) << 16);
    o.z = (uint_t)f2bf(fmaxf(fmaf(acc[4], ndv, b1.x), 0.f)) |
          ((uint_t)f2bf(fmaxf(fmaf(acc[5], ndv, b1.y), 0.f)) << 16);
    o.w = (uint_t)f2bf(fmaxf(fmaf(acc[6], ndv, b1.z), 0.f)) |
          ((uint_t)f2bf(fmaxf(fmaf(acc[7], ndv, b1.w), 0.f)) << 16);
    *((uint4*)(H + (size_t)v * 64) + l) = o;
  }
}

// ---------------------------------------------------------------------------
// 6. Segmented pool over sorted gid (bf16 H)
// ---------------------------------------------------------------------------
__global__ __launch_bounds__(256) void pool_seg_kernel(
    const ushort_t* __restrict__ H, const int* __restrict__ gid,
    float* __restrict__ pooled, float* __restrict__ counts, int n) {
  int wid = (blockIdx.x * blockDim.x + threadIdx.x) >> 6;
  int j = threadIdx.x & 63;
  int s = wid * PCHUNK;
  if (s >= n) return;
  int e = min(s + PCHUNK, n);
  float acc = 0.0f;
  int cur = gid[s];
  int runlen = 0;
  for (int node = s; node < e; ++node) {
    int g = gid[node];
    if (g != cur) {
      atomicAdd(&pooled[cur * 64 + j], acc);
      if (j == 0) atomicAdd(&counts[cur], (float)runlen);
      acc = 0.0f;
      runlen = 0;
      cur = g;
    }
    acc += bflo((uint_t)H[(size_t)node * 64 + j]);
    ++runlen;
  }
  atomicAdd(&pooled[cur * 64 + j], acc);
  if (j == 0) atomicAdd(&counts[cur], (float)runlen);
}

// ---------------------------------------------------------------------------
// 7. MLP head
// ---------------------------------------------------------------------------
__global__ __launch_bounds__(256) void mlp_kernel(
    const float* __restrict__ pooled, const float* __restrict__ counts,
    const float* __restrict__ Dw1, const float* __restrict__ Db1,
    const float* __restrict__ Dw2, const float* __restrict__ Db2,
    const float* __restrict__ Dw3, const float* __restrict__ Db3,
    float* __restrict__ out) {
  int g = blockIdx.x * blockDim.x + threadIdx.x;
  if (g < G_GRAPHS) {
    float inv = 1.0f / fmaxf(counts[g], 1.0f);
    float p[64];
#pragma unroll
    for (int k = 0; k < 64; ++k) p[k] = pooled[g * 64 + k] * inv;
    float h1[16];
#pragma unroll
    for (int o = 0; o < 16; ++o) {
      float a = Db1[o];
      for (int k = 0; k < 64; ++k) a = fmaf(p[k], Dw1[k * 16 + o], a);
      h1[o] = fmaxf(a, 0.0f);
    }
    float h2[8];
#pragma unroll
    for (int o = 0; o < 8; ++o) {
      float a = Db2[o];
      for (int k = 0; k < 16; ++k) a = fmaf(h1[k], Dw2[k * 8 + o], a);
      h2[o] = fmaxf(a, 0.0f);
    }
    float a = Db3[0];
#pragma unroll
    for (int k = 0; k < 8; ++k) a = fmaf(h2[k], Dw3[k], a);
    out[g] = 1.0f / (1.0f + expf(-a));
  }
}

// ---------------------------------------------------------------------------
extern "C" void kernel_launch(void* const* d_in, const int* in_sizes, int n_in,
                              void* d_out, int out_size, void* d_ws, size_t ws_size,
                              hipStream_t stream) {
  const float* x   = (const float*)d_in[0];
  const int*   src = (const int*)  d_in[1];
  const int*   dst = (const int*)  d_in[2];
  const float* ew  = (const float*)d_in[3];
  const int*   gid = (const int*)  d_in[4];
  const float* W1  = (const float*)d_in[5];
  const float* b1  = (const float*)d_in[6];
  const float* W2  = (const float*)d_in[7];
  const float* b2  = (const float*)d_in[8];
  const float* W3  = (const float*)d_in[9];
  const float* b3  = (const float*)d_in[10];
  const float* Dw1 = (const float*)d_in[11];
  const float* Db1 = (const float*)d_in[12];
  const float* Dw2 = (const float*)d_in[13];
  const float* Db2 = (const float*)d_in[14];
  const float* Dw3 = (const float*)d_in[15];
  const float* Db3 = (const float*)d_in[16];
  float* out = (float*)d_out;

  // workspace layout
  char* ws = (char*)d_ws;
  ushort_t* Tb   = (ushort_t*)ws;                       // N*64 bf16 (12.8 MB)
  ushort_t* Hb   = Tb + (size_t)N_NODES * 64;           // N*64 bf16 (12.8 MB)
  float* ns      = (float*)(Hb + (size_t)N_NODES * 64); // N
  float* nd      = ns + N_NODES;                        // N
  float* pooled  = nd + N_NODES;                        // G*64
  float* counts  = pooled + G_GRAPHS * 64;              // G
  int*   cnt_in  = (int*)(counts + G_GRAPHS);           // N
  int*   row_ptr = cnt_in + N_NODES;                    // N
  int*   bsums   = row_ptr + N_NODES;                   // 128
  uint2* csr     = (uint2*)(bsums + 128);               // E (12.8 MB)
  // partials [HB][N] ints = 25.6 MB == Tb+Hb exactly (dead until gemm1)
  int*   partials = (int*)Tb;

  const int NTILES  = N_NODES / 16;                     // 6250
  const int NB_N    = (N_NODES + 255) / 256;
  const int NB_SCAN = (N_NODES + SCAN_CH - 1) / SCAN_CH;
  const int NB_HIST = HR * HB;                          // 832
  const int NB_GEMM = (NTILES + 3) / 4;
  const int NB_GATH = (N_NODES * 64 + 255) / 256;
  const int NB_POOL = (PWAVES * 64) / 256;

  // ---- phase 1: dst histogram -> cnt_in/nd -> row_ptr -> coff -> place
  hist_kernel<<<NB_HIST, 256, 0, stream>>>(dst, partials);
  reduce_dst_kernel<<<NB_N, 256, 0, stream>>>(partials, cnt_in, nd);
  scanA_kernel<<<NB_SCAN, 256, 0, stream>>>(cnt_in, row_ptr, bsums, N_NODES);
  scanB_kernel<<<1, 256, 0, stream>>>(bsums, NB_SCAN);
  scanC_kernel<<<NB_N, 256, 0, stream>>>(row_ptr, bsums, N_NODES);
  coff_kernel<<<NB_N, 256, 0, stream>>>(row_ptr, partials);
  place_kernel<<<NB_HIST, 256, 0, stream>>>(src, dst, ew, partials, csr);

  // ---- phase 2: src histogram -> ns (partials region reused, then dead)
  hist_kernel<<<NB_HIST, 256, 0, stream>>>(src, partials);
  reduce_src_kernel<<<NB_N, 256, 0, stream>>>(partials, ns);

  // ---- layer 1: x(fp32,128) -> Tb -> Hb
  gemm_mfma_kernel<IN_F, true><<<NB_GEMM, 256, 0, stream>>>(x, W1, ns, Tb, NTILES);
  gather_kernel<<<NB_GATH, 256, 0, stream>>>(csr, row_ptr, cnt_in, Tb, nd, b1, Hb, N_NODES);
  // ---- layer 2
  gemm_mfma_kernel<H_F, false><<<NB_GEMM, 256, 0, stream>>>(Hb, W2, ns, Tb, NTILES);
  gather_kernel<<<NB_GATH, 256, 0, stream>>>(csr, row_ptr, cnt_in, Tb, nd, b2, Hb, N_NODES);
  // ---- layer 3
  gemm_mfma_kernel<H_F, false><<<NB_GEMM, 256, 0, stream>>>(Hb, W3, ns, Tb, NTILES);
  gather_kernel<<<NB_GATH, 256, 0, stream>>>(csr, row_ptr, cnt_in, Tb, nd, b3, Hb, N_NODES);

  // ---- pool + MLP
  hipMemsetAsync(pooled, 0, (size_t)(G_GRAPHS * 64 + G_GRAPHS) * sizeof(float), stream);
  pool_seg_kernel<<<NB_POOL, 256, 0, stream>>>(Hb, gid, pooled, counts, N_NODES);
  mlp_kernel<<<1, 256, 0, stream>>>(pooled, counts, Dw1, Db1, Dw2, Db2, Dw3, Db3, out);
}

// Round 7
// 422.266 us; speedup vs baseline: 1.2241x; 1.0243x over previous
//
#include <hip/hip_runtime.h>
#include <math.h>

#define N_NODES 100000
#define N_EDGES 1600000
#define G_GRAPHS 256
#define IN_F 128
#define H_F 64

#define SCAN_CH 1024
#define PWAVES 2048
#define PCHUNK ((N_NODES + PWAVES - 1) / PWAVES)

// histogram / placement partitioning
#define HRANGE 8192            // nodes per LDS window (32 KB)
#define HR 13                  // ceil(100000/8192)
#define HB 64                  // edge chunks
#define HCHUNK (N_EDGES / HB)  // 25000, divisible by 4

typedef unsigned int uint_t;
typedef unsigned short ushort_t;
typedef __attribute__((ext_vector_type(8))) short short8;
typedef __attribute__((ext_vector_type(4))) float floatx4;

__device__ __forceinline__ ushort_t f2bf(float f) {  // round-to-nearest-even
  uint_t u = __float_as_uint(f);
  uint_t r = (u + 0x7fffu + ((u >> 16) & 1u)) >> 16;
  return (ushort_t)r;
}
__device__ __forceinline__ float bflo(uint_t u) { return __uint_as_float(u << 16); }
__device__ __forceinline__ float bfhi(uint_t u) { return __uint_as_float(u & 0xffff0000u); }

// ---------------------------------------------------------------------------
// 1a. dst histogram + rank capture: partials[b][v] = count, rank[e] = local rank
//     grid = HR * HB
// ---------------------------------------------------------------------------
__global__ __launch_bounds__(256) void hist_rank_kernel(
    const int* __restrict__ keys, int* __restrict__ partials,
    int* __restrict__ rank) {
  __shared__ int hist[HRANGE];
  const int r = blockIdx.x / HB;
  const int b = blockIdx.x % HB;
  const int base = r * HRANGE;
  const int width = min(base + HRANGE, N_NODES) - base;

  for (int i = threadIdx.x; i < HRANGE; i += 256) hist[i] = 0;
  __syncthreads();

  const int e0 = b * HCHUNK;
  const uint4* k4 = (const uint4*)(keys + e0);
  for (int i = threadIdx.x; i < HCHUNK / 4; i += 256) {
    uint4 v = k4[i];
    int e = e0 + i * 4;
    int t;
    t = (int)v.x - base; if ((unsigned)t < (unsigned)width) rank[e]     = atomicAdd(&hist[t], 1);
    t = (int)v.y - base; if ((unsigned)t < (unsigned)width) rank[e + 1] = atomicAdd(&hist[t], 1);
    t = (int)v.z - base; if ((unsigned)t < (unsigned)width) rank[e + 2] = atomicAdd(&hist[t], 1);
    t = (int)v.w - base; if ((unsigned)t < (unsigned)width) rank[e + 3] = atomicAdd(&hist[t], 1);
  }
  __syncthreads();

  int* outp = partials + (size_t)b * N_NODES + base;
  for (int i = threadIdx.x; i < width; i += 256) outp[i] = hist[i];
}

// 1b. plain histogram (for src degrees)
__global__ __launch_bounds__(256) void hist_kernel(
    const int* __restrict__ keys, int* __restrict__ partials) {
  __shared__ int hist[HRANGE];
  const int r = blockIdx.x / HB;
  const int b = blockIdx.x % HB;
  const int base = r * HRANGE;
  const int width = min(base + HRANGE, N_NODES) - base;

  for (int i = threadIdx.x; i < HRANGE; i += 256) hist[i] = 0;
  __syncthreads();

  const uint4* k4 = (const uint4*)(keys + b * HCHUNK);
  for (int i = threadIdx.x; i < HCHUNK / 4; i += 256) {
    uint4 v = k4[i];
    int t;
    t = (int)v.x - base; if ((unsigned)t < (unsigned)width) atomicAdd(&hist[t], 1);
    t = (int)v.y - base; if ((unsigned)t < (unsigned)width) atomicAdd(&hist[t], 1);
    t = (int)v.z - base; if ((unsigned)t < (unsigned)width) atomicAdd(&hist[t], 1);
    t = (int)v.w - base; if ((unsigned)t < (unsigned)width) atomicAdd(&hist[t], 1);
  }
  __syncthreads();

  int* outp = partials + (size_t)b * N_NODES + base;
  for (int i = threadIdx.x; i < width; i += 256) outp[i] = hist[i];
}

// reduce dst partials -> cnt_in + nd
__global__ __launch_bounds__(256) void reduce_dst_kernel(
    const int* __restrict__ partials, int* __restrict__ cnt_in,
    float* __restrict__ nd) {
  int v = blockIdx.x * blockDim.x + threadIdx.x;
  if (v >= N_NODES) return;
  const int* p = partials + v;
  int s = 0;
#pragma unroll
  for (int b = 0; b < HB; ++b) s += p[(size_t)b * N_NODES];
  cnt_in[v] = s;
  nd[v] = rsqrtf(fmaxf((float)s, 1.0f));
}

// reduce src partials -> ns
__global__ __launch_bounds__(256) void reduce_src_kernel(
    const int* __restrict__ partials, float* __restrict__ ns) {
  int v = blockIdx.x * blockDim.x + threadIdx.x;
  if (v >= N_NODES) return;
  const int* p = partials + v;
  int s = 0;
#pragma unroll
  for (int b = 0; b < HB; ++b) s += p[(size_t)b * N_NODES];
  ns[v] = rsqrtf(fmaxf((float)s, 1.0f));
}

// ---------------------------------------------------------------------------
// 2. Exclusive scan of cnt_in -> row_ptr
// ---------------------------------------------------------------------------
__global__ __launch_bounds__(256) void scanA_kernel(
    const int* __restrict__ in, int* __restrict__ out, int* __restrict__ bsums, int n) {
  __shared__ int ts[256];
  const int tid = threadIdx.x;
  const int base = blockIdx.x * SCAN_CH + tid * 4;
  int v[4], pre[4], s = 0;
#pragma unroll
  for (int k = 0; k < 4; ++k) {
    v[k] = (base + k < n) ? in[base + k] : 0;
    pre[k] = s;
    s += v[k];
  }
  ts[tid] = s;
  __syncthreads();
  for (int off = 1; off < 256; off <<= 1) {
    int t = (tid >= off) ? ts[tid - off] : 0;
    __syncthreads();
    ts[tid] += t;
    __syncthreads();
  }
  int excl = (tid == 0) ? 0 : ts[tid - 1];
#pragma unroll
  for (int k = 0; k < 4; ++k)
    if (base + k < n) out[base + k] = excl + pre[k];
  if (tid == 255) bsums[blockIdx.x] = ts[255];
}

__global__ __launch_bounds__(256) void scanB_kernel(int* __restrict__ bsums, int nb) {
  __shared__ int ts[256];
  const int tid = threadIdx.x;
  ts[tid] = (tid < nb) ? bsums[tid] : 0;
  __syncthreads();
  for (int off = 1; off < 256; off <<= 1) {
    int t = (tid >= off) ? ts[tid - off] : 0;
    __syncthreads();
    ts[tid] += t;
    __syncthreads();
  }
  if (tid < nb) bsums[tid] = (tid == 0) ? 0 : ts[tid - 1];
}

__global__ __launch_bounds__(256) void scanC_kernel(
    int* __restrict__ out, const int* __restrict__ bsums, int n) {
  int i = blockIdx.x * blockDim.x + threadIdx.x;
  if (i < n) out[i] += bsums[i / SCAN_CH];
}

// ---------------------------------------------------------------------------
// 3a. In-place chunk offsets: partials[b][v] := row_ptr[v] + sum_{b'<b} partials[b'][v]
// ---------------------------------------------------------------------------
__global__ __launch_bounds__(256) void coff_kernel(
    const int* __restrict__ row_ptr, int* __restrict__ partials) {
  int v = blockIdx.x * blockDim.x + threadIdx.x;
  if (v >= N_NODES) return;
  int run = row_ptr[v];
#pragma unroll
  for (int b = 0; b < HB; ++b) {
    int* p = partials + (size_t)b * N_NODES + v;
    int c = *p;
    *p = run;
    run += c;
  }
}

// ---------------------------------------------------------------------------
// 3b. Placement: one thread per edge, atomic-free.
//     slot = coff[b][dst[e]] + rank[e]
// ---------------------------------------------------------------------------
__global__ __launch_bounds__(256) void place_kernel(
    const int* __restrict__ src, const int* __restrict__ dst,
    const float* __restrict__ ew, const int* __restrict__ coff,
    const int* __restrict__ rank, uint2* __restrict__ csr) {
  int e = blockIdx.x * blockDim.x + threadIdx.x;
  if (e >= N_EDGES) return;
  int b = e / HCHUNK;
  int d = dst[e];
  int slot = coff[(size_t)b * N_NODES + d] + rank[e];
  csr[slot] = make_uint2((uint_t)src[e], __float_as_uint(ew[e]));
}

// ---------------------------------------------------------------------------
// 4. MFMA GEMM: T[i,:] = bf16(ns[i] * (X[i,:] @ W))
// ---------------------------------------------------------------------------
template <int K, bool AFP32>
__global__ __launch_bounds__(256) void gemm_mfma_kernel(
    const void* __restrict__ Xin, const float* __restrict__ W,
    const float* __restrict__ ns, ushort_t* __restrict__ T, int ntiles) {
  constexpr int CH = K / 32;
  constexpr int WROW = K + 8;
  __shared__ __align__(16) ushort_t Wt[64 * WROW];
  const int tid = threadIdx.x;

  for (int i = tid; i < K * 64; i += 256) {
    int k = i >> 6, nn = i & 63;
    Wt[nn * WROW + k] = f2bf(W[i]);
  }
  __syncthreads();

  const int wave = tid >> 6;
  const int lane = tid & 63;
  const int tile = blockIdx.x * 4 + wave;
  if (tile >= ntiles) return;
  const int m = lane & 15;
  const int q = lane >> 4;
  const int node0 = tile * 16;

  short8 afrag[CH];
  if (AFP32) {
    const float* xr = (const float*)Xin + (size_t)(node0 + m) * K + q * 8;
#pragma unroll
    for (int c = 0; c < CH; ++c) {
      float4 xa = *(const float4*)(xr + c * 32);
      float4 xb = *(const float4*)(xr + c * 32 + 4);
      short8 a;
      a[0] = (short)f2bf(xa.x); a[1] = (short)f2bf(xa.y);
      a[2] = (short)f2bf(xa.z); a[3] = (short)f2bf(xa.w);
      a[4] = (short)f2bf(xb.x); a[5] = (short)f2bf(xb.y);
      a[6] = (short)f2bf(xb.z); a[7] = (short)f2bf(xb.w);
      afrag[c] = a;
    }
  } else {
    const ushort_t* xr = (const ushort_t*)Xin + (size_t)(node0 + m) * K + q * 8;
#pragma unroll
    for (int c = 0; c < CH; ++c)
      afrag[c] = *(const short8*)(xr + c * 32);
  }

  floatx4 acc[4];
#pragma unroll
  for (int t = 0; t < 4; ++t) acc[t] = (floatx4){0.f, 0.f, 0.f, 0.f};

#pragma unroll
  for (int t = 0; t < 4; ++t) {
    const ushort_t* wr = &Wt[(t * 16 + m) * WROW + q * 8];
#pragma unroll
    for (int c = 0; c < CH; ++c) {
      short8 bfrag = *(const short8*)(wr + c * 32);
      acc[t] = __builtin_amdgcn_mfma_f32_16x16x32_bf16(afrag[c], bfrag, acc[t], 0, 0, 0);
    }
  }

  float4 nsv = *(const float4*)(ns + node0 + q * 4);
  const float nsa[4] = {nsv.x, nsv.y, nsv.z, nsv.w};
#pragma unroll
  for (int t = 0; t < 4; ++t) {
#pragma unroll
    for (int r = 0; r < 4; ++r) {
      int node = node0 + q * 4 + r;
      T[(size_t)node * 64 + t * 16 + m] = f2bf(acc[t][r] * nsa[r]);
    }
  }
}

// ---------------------------------------------------------------------------
// 5. CSR gather (bf16 T), 16 edges in flight per wave-iteration.
// ---------------------------------------------------------------------------
__global__ __launch_bounds__(256) void gather_kernel(
    const uint2* __restrict__ csr, const int* __restrict__ row_ptr,
    const int* __restrict__ cnt_in, const ushort_t* __restrict__ T,
    const float* __restrict__ nd, const float* __restrict__ b,
    ushort_t* __restrict__ H, int n) {
  int id = blockIdx.x * blockDim.x + threadIdx.x;
  int v = id >> 6;
  if (v >= n) return;
  const int lane = threadIdx.x & 63;
  const int g = lane >> 3, l = lane & 7;
  const int start = row_ptr[v];
  const int cnt = cnt_in[v];

  float acc[8] = {0, 0, 0, 0, 0, 0, 0, 0};
  for (int k = 0; k < cnt; k += 16) {
    int i1 = k + g, i2 = k + 8 + g;
    uint2 e1 = csr[start + min(i1, cnt - 1)];
    uint2 e2 = csr[start + min(i2, cnt - 1)];
    float w1 = (i1 < cnt) ? __uint_as_float(e1.y) : 0.0f;
    float w2 = (i2 < cnt) ? __uint_as_float(e2.y) : 0.0f;
    uint4 p1 = *((const uint4*)(T + (size_t)e1.x * 64) + l);
    uint4 p2 = *((const uint4*)(T + (size_t)e2.x * 64) + l);
    acc[0] = fmaf(bflo(p1.x), w1, acc[0]);
    acc[1] = fmaf(bfhi(p1.x), w1, acc[1]);
    acc[2] = fmaf(bflo(p1.y), w1, acc[2]);
    acc[3] = fmaf(bfhi(p1.y), w1, acc[3]);
    acc[4] = fmaf(bflo(p1.z), w1, acc[4]);
    acc[5] = fmaf(bfhi(p1.z), w1, acc[5]);
    acc[6] = fmaf(bflo(p1.w), w1, acc[6]);
    acc[7] = fmaf(bfhi(p1.w), w1, acc[7]);
    acc[0] = fmaf(bflo(p2.x), w2, acc[0]);
    acc[1] = fmaf(bfhi(p2.x), w2, acc[1]);
    acc[2] = fmaf(bflo(p2.y), w2, acc[2]);
    acc[3] = fmaf(bfhi(p2.y), w2, acc[3]);
    acc[4] = fmaf(bflo(p2.z), w2, acc[4]);
    acc[5] = fmaf(bfhi(p2.z), w2, acc[5]);
    acc[6] = fmaf(bflo(p2.w), w2, acc[6]);
    acc[7] = fmaf(bfhi(p2.w), w2, acc[7]);
  }
#pragma unroll
  for (int off = 8; off < 64; off <<= 1) {
#pragma unroll
    for (int i = 0; i < 8; ++i) acc[i] += __shfl_xor(acc[i], off, 64);
  }
  if (g == 0) {
    float ndv = nd[v];
    float4 b0 = *(const float4*)&b[l * 8];
    float4 b1 = *(const float4*)&b[l * 8 + 4];
    uint4 o;
    o.x = (uint_t)f2bf(fmaxf(fmaf(acc[0], ndv, b0.x), 0.f)) |
          ((uint_t)f2bf(fmaxf(fmaf(acc[1], ndv, b0.y), 0.f)) << 16);
    o.y = (uint_t)f2bf(fmaxf(fmaf(acc[2], ndv, b0.z), 0.f)) |
          ((uint_t)f2bf(fmaxf(fmaf(acc[3], ndv, b0.w), 0.f)) << 16);
    o.z = (uint_t)f2bf(fmaxf(fmaf(acc[4], ndv, b1.x), 0.f)) |
          ((uint_t)f2bf(fmaxf(fmaf(acc[5], ndv, b1.y), 0.f)) << 16);
    o.w = (uint_t)f2bf(fmaxf(fmaf(acc[6], ndv, b1.z), 0.f)) |
          ((uint_t)f2bf(fmaxf(fmaf(acc[7], ndv, b1.w), 0.f)) << 16);
    *((uint4*)(H + (size_t)v * 64) + l) = o;
  }
}

// ---------------------------------------------------------------------------
// 6. Segmented pool over sorted gid (bf16 H)
// ---------------------------------------------------------------------------
__global__ __launch_bounds__(256) void pool_seg_kernel(
    const ushort_t* __restrict__ H, const int* __restrict__ gid,
    float* __restrict__ pooled, float* __restrict__ counts, int n) {
  int wid = (blockIdx.x * blockDim.x + threadIdx.x) >> 6;
  int j = threadIdx.x & 63;
  int s = wid * PCHUNK;
  if (s >= n) return;
  int e = min(s + PCHUNK, n);
  float acc = 0.0f;
  int cur = gid[s];
  int runlen = 0;
  for (int node = s; node < e; ++node) {
    int g = gid[node];
    if (g != cur) {
      atomicAdd(&pooled[cur * 64 + j], acc);
      if (j == 0) atomicAdd(&counts[cur], (float)runlen);
      acc = 0.0f;
      runlen = 0;
      cur = g;
    }
    acc += bflo((uint_t)H[(size_t)node * 64 + j]);
    ++runlen;
  }
  atomicAdd(&pooled[cur * 64 + j], acc);
  if (j == 0) atomicAdd(&counts[cur], (float)runlen);
}

// ---------------------------------------------------------------------------
// 7. MLP head
// ---------------------------------------------------------------------------
__global__ __launch_bounds__(256) void mlp_kernel(
    const float* __restrict__ pooled, const float* __restrict__ counts,
    const float* __restrict__ Dw1, const float* __restrict__ Db1,
    const float* __restrict__ Dw2, const float* __restrict__ Db2,
    const float* __restrict__ Dw3, const float* __restrict__ Db3,
    float* __restrict__ out) {
  int g = blockIdx.x * blockDim.x + threadIdx.x;
  if (g < G_GRAPHS) {
    float inv = 1.0f / fmaxf(counts[g], 1.0f);
    float p[64];
#pragma unroll
    for (int k = 0; k < 64; ++k) p[k] = pooled[g * 64 + k] * inv;
    float h1[16];
#pragma unroll
    for (int o = 0; o < 16; ++o) {
      float a = Db1[o];
      for (int k = 0; k < 64; ++k) a = fmaf(p[k], Dw1[k * 16 + o], a);
      h1[o] = fmaxf(a, 0.0f);
    }
    float h2[8];
#pragma unroll
    for (int o = 0; o < 8; ++o) {
      float a = Db2[o];
      for (int k = 0; k < 16; ++k) a = fmaf(h1[k], Dw2[k * 8 + o], a);
      h2[o] = fmaxf(a, 0.0f);
    }
    float a = Db3[0];
#pragma unroll
    for (int k = 0; k < 8; ++k) a = fmaf(h2[k], Dw3[k], a);
    out[g] = 1.0f / (1.0f + expf(-a));
  }
}

// ---------------------------------------------------------------------------
extern "C" void kernel_launch(void* const* d_in, const int* in_sizes, int n_in,
                              void* d_out, int out_size, void* d_ws, size_t ws_size,
                              hipStream_t stream) {
  const float* x   = (const float*)d_in[0];
  const int*   src = (const int*)  d_in[1];
  const int*   dst = (const int*)  d_in[2];
  const float* ew  = (const float*)d_in[3];
  const int*   gid = (const int*)  d_in[4];
  const float* W1  = (const float*)d_in[5];
  const float* b1  = (const float*)d_in[6];
  const float* W2  = (const float*)d_in[7];
  const float* b2  = (const float*)d_in[8];
  const float* W3  = (const float*)d_in[9];
  const float* b3  = (const float*)d_in[10];
  const float* Dw1 = (const float*)d_in[11];
  const float* Db1 = (const float*)d_in[12];
  const float* Dw2 = (const float*)d_in[13];
  const float* Db2 = (const float*)d_in[14];
  const float* Dw3 = (const float*)d_in[15];
  const float* Db3 = (const float*)d_in[16];
  float* out = (float*)d_out;

  // workspace layout
  char* ws = (char*)d_ws;
  ushort_t* Tb   = (ushort_t*)ws;                       // N*64 bf16 (12.8 MB)
  ushort_t* Hb   = Tb + (size_t)N_NODES * 64;           // N*64 bf16 (12.8 MB)
  float* ns      = (float*)(Hb + (size_t)N_NODES * 64); // N
  float* nd      = ns + N_NODES;                        // N
  float* pooled  = nd + N_NODES;                        // G*64
  float* counts  = pooled + G_GRAPHS * 64;              // G
  int*   cnt_in  = (int*)(counts + G_GRAPHS);           // N
  int*   row_ptr = cnt_in + N_NODES;                    // N
  int*   bsums   = row_ptr + N_NODES;                   // 128
  uint2* csr     = (uint2*)(bsums + 128);               // E (12.8 MB)
  int*   rank    = (int*)(csr + N_EDGES);               // E (6.4 MB)
  // partials [HB][N] ints = 25.6 MB == Tb+Hb exactly (dead until gemm1)
  int*   partials = (int*)Tb;

  const int NTILES  = N_NODES / 16;                     // 6250
  const int NB_N    = (N_NODES + 255) / 256;
  const int NB_E    = (N_EDGES + 255) / 256;
  const int NB_SCAN = (N_NODES + SCAN_CH - 1) / SCAN_CH;
  const int NB_HIST = HR * HB;                          // 832
  const int NB_GEMM = (NTILES + 3) / 4;
  const int NB_GATH = (N_NODES * 64 + 255) / 256;
  const int NB_POOL = (PWAVES * 64) / 256;

  // ---- phase 1: dst histogram(+rank) -> cnt_in/nd -> row_ptr -> coff -> place
  hist_rank_kernel<<<NB_HIST, 256, 0, stream>>>(dst, partials, rank);
  reduce_dst_kernel<<<NB_N, 256, 0, stream>>>(partials, cnt_in, nd);
  scanA_kernel<<<NB_SCAN, 256, 0, stream>>>(cnt_in, row_ptr, bsums, N_NODES);
  scanB_kernel<<<1, 256, 0, stream>>>(bsums, NB_SCAN);
  scanC_kernel<<<NB_N, 256, 0, stream>>>(row_ptr, bsums, N_NODES);
  coff_kernel<<<NB_N, 256, 0, stream>>>(row_ptr, partials);
  place_kernel<<<NB_E, 256, 0, stream>>>(src, dst, ew, partials, rank, csr);

  // ---- phase 2: src histogram -> ns (partials region reused, then dead)
  hist_kernel<<<NB_HIST, 256, 0, stream>>>(src, partials);
  reduce_src_kernel<<<NB_N, 256, 0, stream>>>(partials, ns);

  // ---- layer 1: x(fp32,128) -> Tb -> Hb
  gemm_mfma_kernel<IN_F, true><<<NB_GEMM, 256, 0, stream>>>(x, W1, ns, Tb, NTILES);
  gather_kernel<<<NB_GATH, 256, 0, stream>>>(csr, row_ptr, cnt_in, Tb, nd, b1, Hb, N_NODES);
  // ---- layer 2
  gemm_mfma_kernel<H_F, false><<<NB_GEMM, 256, 0, stream>>>(Hb, W2, ns, Tb, NTILES);
  gather_kernel<<<NB_GATH, 256, 0, stream>>>(csr, row_ptr, cnt_in, Tb, nd, b2, Hb, N_NODES);
  // ---- layer 3
  gemm_mfma_kernel<H_F, false><<<NB_GEMM, 256, 0, stream>>>(Hb, W3, ns, Tb, NTILES);
  gather_kernel<<<NB_GATH, 256, 0, stream>>>(csr, row_ptr, cnt_in, Tb, nd, b3, Hb, N_NODES);

  // ---- pool + MLP
  hipMemsetAsync(pooled, 0, (size_t)(G_GRAPHS * 64 + G_GRAPHS) * sizeof(float), stream);
  pool_seg_kernel<<<NB_POOL, 256, 0, stream>>>(Hb, gid, pooled, counts, N_NODES);
  mlp_kernel<<<1, 256, 0, stream>>>(pooled, counts, Dw1, Db1, Dw2, Db2, Dw3, Db3, out);
}